// Round 9
// baseline (165.189 us; speedup 1.0000x reference)
//
#include <hip/hip_runtime.h>
#include <hip/hip_bf16.h>
#include <math.h>

#define B_ 2
#define H_ 8
#define N_ 2048
#define D_ 64
#define BH_ 16
#define NT_ (N_/64)
#define LS 72
#define LSW (LS/2)

typedef __attribute__((ext_vector_type(8))) short short8;
typedef __attribute__((ext_vector_type(4))) float float4v;
typedef __attribute__((ext_vector_type(2))) float float2v;

__device__ __forceinline__ float2v splat2(float s){ float2v v; v.x=s; v.y=s; return v; }

__device__ __forceinline__ unsigned packbf2(float a, float b){
  __hip_bfloat162 h = __float22bfloat162_rn(make_float2(a, b));
  return *(unsigned*)&h;
}
__device__ __forceinline__ void split2(float a, float b, unsigned& hi, unsigned& lo){
  hi = packbf2(a, b);
  float ha = __uint_as_float(hi << 16);
  float hb = __uint_as_float(hi & 0xFFFF0000u);
  lo = packbf2(a - ha, b - hb);
}
__device__ __forceinline__ void load_split8(const float* p, short8& hi8, short8& lo8){
  float4v v0 = *(const float4v*)p;
  float4v v1 = *(const float4v*)(p + 4);
  unsigned h0,h1,h2,h3,l0,l1,l2,l3;
  split2(v0.x, v0.y, h0, l0);
  split2(v0.z, v0.w, h1, l1);
  split2(v1.x, v1.y, h2, l2);
  split2(v1.z, v1.w, h3, l3);
  unsigned ph[4] = {h0,h1,h2,h3};
  unsigned pl[4] = {l0,l1,l2,l3};
  hi8 = *(short8*)ph;
  lo8 = *(short8*)pl;
}

// packed-pair score: (1 + acos(clip(qk)))^(-5) on two values at once.
__device__ __forceinline__ float2v score2(float2v qk){
  float2v ax;
  ax.x = fminf(fabsf(qk.x), 1.0f - 1e-7f);
  ax.y = fminf(fabsf(qk.y), 1.0f - 1e-7f);
  float2v p = __builtin_elementwise_fma(
                __builtin_elementwise_fma(
                  __builtin_elementwise_fma(splat2(-0.0187293f), ax, splat2(0.0742610f)),
                  ax, splat2(-0.2121144f)),
                ax, splat2(1.5707288f));
  float2v u = __builtin_elementwise_fma(ax, splat2(-1.0f), splat2(1.0f));
  float2v t;
  t.x = __builtin_amdgcn_sqrtf(u.x);
  t.y = __builtin_amdgcn_sqrtf(u.y);
  float2v t2 = t * p;
  float2v gn = __builtin_elementwise_fma(t2, splat2(-1.0f), splat2(3.14159265358979f));
  float2v g;
  g.x = (qk.x >= 0.0f) ? t2.x : gn.x;
  g.y = (qk.y >= 0.0f) ? t2.y : gn.y;
  float2v w1 = g + splat2(1.0f);
  float2v w2 = w1 * w1;
  float2v w4 = w2 * w2;
  float2v w5 = w4 * w1;
  float2v r;
  r.x = __builtin_amdgcn_rcpf(w5.x);
  r.y = __builtin_amdgcn_rcpf(w5.y);
  return r;
}

// scalar masked variant (fallback tier only)
__device__ __forceinline__ float score_fn_m(float qk, float masked){
  float ax = fminf(fabsf(qk), 1.0f - 1e-7f);
  float t  = __builtin_amdgcn_sqrtf(1.0f - ax);
  float p  = __builtin_fmaf(__builtin_fmaf(__builtin_fmaf(-0.0187293f, ax, 0.0742610f),
                                           ax, -0.2121144f), ax, 1.5707288f);
  float t2 = t * p;
  float g  = (qk >= 0.0f) ? t2 : (3.14159265358979f - t2);
  g = (masked != 0.0f) ? 10000.0f : g;
  float w1 = 1.0f + g;
  float w2 = w1*w1;
  float w4 = w2*w2;
  return __builtin_amdgcn_rcpf(w4*w1);
}

// k0: one-time fp32 -> bf16 hi/lo split of Q and K
__global__ __launch_bounds__(256) void k0_split(
    const float* __restrict__ Q, const float* __restrict__ K,
    unsigned short* __restrict__ Qh, unsigned short* __restrict__ Ql,
    unsigned short* __restrict__ Kh, unsigned short* __restrict__ Kl)
{
  size_t i = (size_t)blockIdx.x*256 + threadIdx.x;
  const size_t tot = (size_t)BH_*N_*D_/8;
  const float* src; unsigned short *dh, *dl;
  if (i < tot){ src = Q; dh = Qh; dl = Ql; }
  else        { src = K; dh = Kh; dl = Kl; i -= tot; }
  short8 hi, lo;
  load_split8(src + i*8, hi, lo);
  *(short8*)&dh[i*8] = hi;
  *(short8*)&dl[i*8] = lo;
}

// k1 (R5 base + chain split): UNMASKED scores -> S, col sums -> ncw.
// Per s-block the 6 MFMAs now form TWO independent 3-deep chains (ca: cc=0,
// cb: cc=1) summed at the end -- halves dependent latency, 8 MFMA streams/wave.
// Do NOT thin the 4-s body (R2/R6 both regressed).
template<bool PRE>
__global__ __launch_bounds__(256) void k1_score(
    const float* __restrict__ Qf, const float* __restrict__ Kf,
    const unsigned short* __restrict__ Qh, const unsigned short* __restrict__ Ql,
    const unsigned short* __restrict__ Kh, const unsigned short* __restrict__ Kl,
    float* __restrict__ ncw, unsigned short* __restrict__ S)
{
  __shared__ float red[64*4];
  const int id = blockIdx.x;
  const int xcd = id & 7;
  const int r0 = id >> 3;             // [0,256)
  const int kt = r0 & 31;
  const int grp = r0 >> 5;            // [0,8)
  const int flat = grp*8 + xcd;       // [0,64)
  const int bh = flat & 15;
  const int rz = flat >> 4;           // [0,4)
  const int tid = threadIdx.x;
  const int wv = tid>>6, lane = tid&63, quad = lane>>4, l15 = lane&15;

  short8 khi[4][2], klo[4][2];
  if constexpr (PRE){
    #pragma unroll
    for (int s=0;s<4;++s){
      const size_t r = (size_t)(bh*N_ + kt*64 + s*16 + l15)*D_ + quad*8;
      khi[s][0] = *(const short8*)&Kh[r];
      khi[s][1] = *(const short8*)&Kh[r+32];
      klo[s][0] = *(const short8*)&Kl[r];
      klo[s][1] = *(const short8*)&Kl[r+32];
    }
  } else {
    #pragma unroll
    for (int s=0;s<4;++s){
      const float* kp = Kf + (size_t)(bh*N_ + kt*64 + s*16 + l15)*D_ + quad*8;
      load_split8(kp,      khi[s][0], klo[s][0]);
      load_split8(kp + 32, khi[s][1], klo[s][1]);
    }
  }

  float2v cs2[4][2];
  #pragma unroll
  for (int s=0;s<4;++s){ cs2[s][0] = splat2(0.f); cs2[s][1] = splat2(0.f); }

  const int iters = NT_/4;
  const int rt0 = rz*iters;

  const size_t qoff0 = (size_t)(bh*N_ + rt0*64 + wv*16 + l15)*D_ + quad*8;
  const unsigned lconst = (unsigned)(((quad>>1)<<7) + (l15<<3) + ((quad&1)<<2));
  unsigned short* Sp = S + ((((size_t)(bh*NT_ + kt)*NT_ + rt0)*4 + wv)<<10) + lconst;

  short8 qh0,qh1,ql0,ql1;
  if constexpr (PRE){
    const unsigned short* qp = Qh + qoff0;
    const unsigned short* lp = Ql + qoff0;
    qh0 = *(const short8*)qp;      qh1 = *(const short8*)(qp+32);
    ql0 = *(const short8*)lp;      ql1 = *(const short8*)(lp+32);
  } else {
    const float* qp = Qf + qoff0;
    load_split8(qp,      qh0, ql0);
    load_split8(qp + 32, qh1, ql1);
  }

  for (int rti=0; rti<iters; ++rti){
    short8 nh0,nh1,nl0,nl1;
    const size_t qoffn = qoff0 + (size_t)(rti + ((rti+1<iters) ? 1 : 0))*4096;
    if constexpr (PRE){
      const unsigned short* qp = Qh + qoffn;
      const unsigned short* lp = Ql + qoffn;
      nh0 = *(const short8*)qp;    nh1 = *(const short8*)(qp+32);
      nl0 = *(const short8*)lp;    nl1 = *(const short8*)(lp+32);
    } else {
      const float* qp = Qf + qoffn;
      load_split8(qp,      nh0, nl0);
      load_split8(qp + 32, nh1, nl1);
    }

    #pragma unroll
    for (int s=0;s<4;++s){
      float4v ca = {0.f,0.f,0.f,0.f};
      float4v cb = {0.f,0.f,0.f,0.f};
      ca = __builtin_amdgcn_mfma_f32_16x16x32_bf16(khi[s][0], qh0, ca, 0,0,0);
      cb = __builtin_amdgcn_mfma_f32_16x16x32_bf16(khi[s][1], qh1, cb, 0,0,0);
      ca = __builtin_amdgcn_mfma_f32_16x16x32_bf16(khi[s][0], ql0, ca, 0,0,0);
      cb = __builtin_amdgcn_mfma_f32_16x16x32_bf16(khi[s][1], ql1, cb, 0,0,0);
      ca = __builtin_amdgcn_mfma_f32_16x16x32_bf16(klo[s][0], qh0, ca, 0,0,0);
      cb = __builtin_amdgcn_mfma_f32_16x16x32_bf16(klo[s][1], qh1, cb, 0,0,0);
      float4v c = ca + cb;
      float2v c01; c01.x = c[0]; c01.y = c[1];
      float2v c23; c23.x = c[2]; c23.y = c[3];
      float2v s01 = score2(c01);
      float2v s23 = score2(c23);
      cs2[s][0] += s01;
      cs2[s][1] += s23;
      uint2 pk;
      pk.x = packbf2(s01.x, s01.y);
      pk.y = packbf2(s23.x, s23.y);
      *(uint2*)(Sp + (s<<8)) = pk;
    }
    Sp += 4096;
    qh0=nh0; qh1=nh1; ql0=nl0; ql1=nl1;
  }

  float cs[4][4];
  #pragma unroll
  for (int s=0;s<4;++s){
    cs[s][0]=cs2[s][0].x; cs[s][1]=cs2[s][0].y;
    cs[s][2]=cs2[s][1].x; cs[s][3]=cs2[s][1].y;
  }

  #pragma unroll
  for (int s=0;s<4;++s)
    #pragma unroll
    for (int i=0;i<4;++i){
      float v2 = cs[s][i];
      v2 += __shfl_xor(v2, 1);
      v2 += __shfl_xor(v2, 2);
      v2 += __shfl_xor(v2, 4);
      v2 += __shfl_xor(v2, 8);
      cs[s][i] = v2;
    }
  if (l15 == 0){
    #pragma unroll
    for (int s=0;s<4;++s)
      #pragma unroll
      for (int i=0;i<4;++i)
        red[(s*16 + quad*4 + i)*4 + wv] = cs[s][i];
  }
  __syncthreads();
  if (tid < 64){
    float t = red[tid*4+0] + red[tid*4+1] + red[tid*4+2] + red[tid*4+3];
    atomicAdd(&ncw[bh*N_ + kt*64 + tid], t);
  }
}

// k2_pack (+XCD swizzle matching k3): Vw written on the XCD that will read it.
__global__ __launch_bounds__(256) void k2_pack(
    const float* __restrict__ V, const float* __restrict__ nc,
    const int* __restrict__ mask, unsigned short* __restrict__ Vw)
{
  __shared__ float T[64*65];
  __shared__ float wrow[64];
  const int id = blockIdx.x;            // 512
  const int xcd = id & 7;
  const int r0 = id >> 3;               // 0..63
  const int bh = (r0 & 1)*8 + xcd;      // XCD = bh%8
  const int mt = r0 >> 1;               // 0..31
  const int tid = threadIdx.x;
  const float* Vg = V + (size_t)bh*N_*D_;
  const float* ncg = nc + (size_t)bh*N_;
  unsigned short* Fb = Vw + ((size_t)(bh*NT_ + mt)*10)*512;

  {
    int m = tid >> 2;
    int d0 = (tid & 3) * 16;
    int gm = mt*64 + m;
    float wm = (mask[(bh>>3)*N_ + gm] == 0) ? 0.0f
             : (1.0f / sqrtf(fmaxf(ncg[gm], 1e-30f)));
    if (d0 == 0) wrow[m] = wm;
    #pragma unroll
    for (int j=0;j<4;++j){
      float4v v = *(const float4v*)(Vg + (size_t)gm*D_ + d0 + j*4);
      T[(d0+j*4+0)*65 + m] = v.x*wm;
      T[(d0+j*4+1)*65 + m] = v.y*wm;
      T[(d0+j*4+2)*65 + m] = v.z*wm;
      T[(d0+j*4+3)*65 + m] = v.w*wm;
    }
  }
  __syncthreads();

  for (int idx = tid; idx < 640; idx += 256){
    int f = idx >> 6, lane = idx & 63;
    int quad = lane >> 4, l15 = lane & 15;
    int s2 = f >> 1, cc = f & 1;
    int m0 = cc*32 + quad*8;
    unsigned pk[4];
    if (s2 < 4){
      int d = s2*16 + l15;
      #pragma unroll
      for (int j=0;j<4;++j)
        pk[j] = packbf2(T[d*65 + m0 + 2*j], T[d*65 + m0 + 2*j + 1]);
    } else if (l15 == 0){
      #pragma unroll
      for (int j=0;j<4;++j)
        pk[j] = packbf2(wrow[m0 + 2*j], wrow[m0 + 2*j + 1]);
    } else {
      pk[0]=pk[1]=pk[2]=pk[3]=0u;
    }
    *(short8*)(Fb + ((size_t)f*64 + lane)*8) = *(short8*)pk;
  }
}

// k3_stage v2: LDS-broadcast Vw staging + XCD swizzle + T14 async split +
// DEPTH-2 S register prefetch (manual unroll-by-2, named sA/sB buffers):
// S loads for it+2 issued at iter it -> ~2 iterations of latency cover.
__global__ __launch_bounds__(1024) void k3_stage(
    const unsigned short* __restrict__ S, const unsigned short* __restrict__ Vw,
    float* __restrict__ out)
{
  __shared__ unsigned short Vs[2*2*10*512];   // 40960 B; overlaid by Red

  const int id = blockIdx.x;            // 256 blocks
  const int xcd = id & 7;
  const int r0 = id >> 3;               // 0..31
  const int bh  = (r0 & 1)*8 + xcd;     // XCD = bh%8
  const int rtp = r0 >> 1;              // 0..15

  const int tid = threadIdx.x;
  const int wvid = tid >> 6;
  const int g    = wvid >> 3;           // kt half: 0 -> kt 0..15, 1 -> 16..31
  const int slot = wvid & 7;            // row slot
  const int lane = tid & 63, quad = lane >> 4, l15 = lane & 15;

  const int row = rtp*128 + slot*16 + l15;
  const int rt  = rtp*2 + (slot>>2);

  const size_t sb0 = ((((size_t)bh*NT_ + g*16)*NT_ + rt)*4 + (size_t)(slot&3))*1024
                   + (size_t)quad*128 + (size_t)l15*8;

  const int gg0 = (tid >= 640) ? 1 : 0;
  const int rem0 = tid - gg0*640;
  const int f0 = rem0 >> 6, ln0 = rem0 & 63;
  const bool has1 = (tid < 256);
  const int rem1 = tid + 384;
  const int f1 = rem1 >> 6, ln1 = rem1 & 63;
  const size_t vwbh = (size_t)bh*NT_;

  float4v acc[4];
  #pragma unroll
  for (int i=0;i<4;++i) acc[i] = (float4v){0.f,0.f,0.f,0.f};
  float4v c5 = {0.f,0.f,0.f,0.f};

  // prologue: stage it=0 synchronously
  {
    short8 a = *(const short8*)&Vw[(((vwbh + gg0*16)*10 + f0) << 9) + ln0*8];
    *(short8*)&Vs[((gg0*10 + f0) << 9) + ln0*8] = a;
    if (has1){
      short8 b = *(const short8*)&Vw[(((vwbh + 16)*10 + f1) << 9) + ln1*8];
      *(short8*)&Vs[((1*10 + f1) << 9) + ln1*8] = b;
    }
  }
  // depth-2 S prefetch: sA holds even iterations, sB holds odd iterations
  short8 sA0 = *(const short8*)&S[sb0];
  short8 sA1 = *(const short8*)&S[sb0 + 512];
  short8 sB0 = *(const short8*)&S[sb0 + 131072];
  short8 sB1 = *(const short8*)&S[sb0 + 131072 + 512];
  __syncthreads();

  #pragma unroll 1
  for (int k2 = 0; k2 < 8; ++k2){
    const int itA = k2*2, itB = k2*2 + 1;

    // ---- sub-iteration A: cur buf 0, next buf 1 ----
    {
      short8 vwa, vwb;
      // Vw staging loads for itA+1 (<=15 always)
      vwa = *(const short8*)&Vw[(((vwbh + (size_t)(gg0*16 + itA + 1))*10 + f0) << 9) + ln0*8];
      if (has1)
        vwb = *(const short8*)&Vw[(((vwbh + (size_t)(16 + itA + 1))*10 + f1) << 9) + ln1*8];
      short8 p0 = sA0, p1 = sA1;
      if (itA + 2 < 16){
        const size_t sb = sb0 + (size_t)(itA+2)*131072;
        sA0 = *(const short8*)&S[sb];
        sA1 = *(const short8*)&S[sb + 512];
      }

      const unsigned short* Fl = &Vs[((0*2 + g)*10) << 9] + (size_t)lane*8;
      short8 va[10];
      #pragma unroll
      for (int f=0; f<10; ++f)
        va[f] = *(const short8*)(Fl + ((size_t)f << 9));

      #pragma unroll
      for (int s2=0;s2<4;++s2){
        acc[s2] = __builtin_amdgcn_mfma_f32_16x16x32_bf16(va[s2*2+0], p0, acc[s2], 0,0,0);
        acc[s2] = __builtin_amdgcn_mfma_f32_16x16x32_bf16(va[s2*2+1], p1, acc[s2], 0,0,0);
      }
      c5 = __builtin_amdgcn_mfma_f32_16x16x32_bf16(va[8], p0, c5, 0,0,0);
      c5 = __builtin_amdgcn_mfma_f32_16x16x32_bf16(va[9], p1, c5, 0,0,0);

      *(short8*)&Vs[(((1*2 + gg0)*10 + f0) << 9) + ln0*8] = vwa;
      if (has1)
        *(short8*)&Vs[(((1*2 + 1)*10 + f1) << 9) + ln1*8] = vwb;
      __syncthreads();
    }

    // ---- sub-iteration B: cur buf 1, next buf 0 ----
    {
      short8 vwa, vwb;
      const bool stage = (itB + 1 < 16);
      if (stage){
        vwa = *(const short8*)&Vw[(((vwbh + (size_t)(gg0*16 + itB + 1))*10 + f0) << 9) + ln0*8];
        if (has1)
          vwb = *(const short8*)&Vw[(((vwbh + (size_t)(16 + itB + 1))*10 + f1) << 9) + ln1*8];
      }
      short8 p0 = sB0, p1 = sB1;
      if (itB + 2 < 16){
        const size_t sb = sb0 + (size_t)(itB+2)*131072;
        sB0 = *(const short8*)&S[sb];
        sB1 = *(const short8*)&S[sb + 512];
      }

      const unsigned short* Fl = &Vs[((1*2 + g)*10) << 9] + (size_t)lane*8;
      short8 va[10];
      #pragma unroll
      for (int f=0; f<10; ++f)
        va[f] = *(const short8*)(Fl + ((size_t)f << 9));

      #pragma unroll
      for (int s2=0;s2<4;++s2){
        acc[s2] = __builtin_amdgcn_mfma_f32_16x16x32_bf16(va[s2*2+0], p0, acc[s2], 0,0,0);
        acc[s2] = __builtin_amdgcn_mfma_f32_16x16x32_bf16(va[s2*2+1], p1, acc[s2], 0,0,0);
      }
      c5 = __builtin_amdgcn_mfma_f32_16x16x32_bf16(va[8], p0, c5, 0,0,0);
      c5 = __builtin_amdgcn_mfma_f32_16x16x32_bf16(va[9], p1, c5, 0,0,0);

      if (stage){
        *(short8*)&Vs[(((0*2 + gg0)*10 + f0) << 9) + ln0*8] = vwa;
        if (has1)
          *(short8*)&Vs[(((0*2 + 1)*10 + f1) << 9) + ln1*8] = vwb;
      }
      __syncthreads();
    }
  }

  // reduce across the two kt halves (Red overlays Vs; safe after last barrier)
  float* Red = (float*)Vs;
  if (g == 1){
    float* Rr = Red + (size_t)(slot*16 + l15)*68;
    #pragma unroll
    for (int s2=0;s2<4;++s2)
      #pragma unroll
      for (int i=0;i<4;++i)
        Rr[s2*16 + quad*4 + i] = acc[s2][i];
    if (quad == 0) Rr[64] = c5[0];
  }
  __syncthreads();
  if (g == 0){
    const float* Rr = Red + (size_t)(slot*16 + l15)*68;
    #pragma unroll
    for (int s2=0;s2<4;++s2)
      #pragma unroll
      for (int i=0;i<4;++i)
        acc[s2][i] += Rr[s2*16 + quad*4 + i];
    float rs = __shfl(c5[0], l15) + Rr[64];
    float inv = 1.0f / fmaxf(rs, 1e-12f);

    float* Og = out + (size_t)bh*N_*D_ + (size_t)row*D_;
    #pragma unroll
    for (int s2=0;s2<4;++s2)
      #pragma unroll
      for (int i=0;i<4;++i)
        Og[s2*16 + quad*4 + i] = acc[s2][i] * inv;
  }
}

// -------- tier C fallback (verified structure, unchanged semantics) --------
__global__ __launch_bounds__(256) void k1_fallback(
    const float* __restrict__ Q, const float* __restrict__ K,
    const int* __restrict__ mask, float* __restrict__ ncw)
{
  __shared__ float msk[64];
  __shared__ float red[64*4];
  const int kt = blockIdx.x, bh = blockIdx.y;
  const int tid = threadIdx.x;
  const int wv = tid>>6, lane = tid&63, quad = lane>>4, l15 = lane&15;

  const float* Qg = Q + (size_t)bh*N_*D_;
  const float* Kg = K + (size_t)bh*N_*D_;

  short8 khi[4][2], klo[4][2];
  #pragma unroll
  for (int s=0;s<4;++s){
    const float* kp = Kg + (size_t)(kt*64 + s*16 + l15)*D_ + quad*8;
    load_split8(kp,      khi[s][0], klo[s][0]);
    load_split8(kp + 32, khi[s][1], klo[s][1]);
  }
  if (tid < 64)
    msk[tid] = (mask[(bh>>3)*N_ + kt*64 + tid] == 0) ? 1.f : 0.f;
  __syncthreads();

  float cs[4][4];
  #pragma unroll
  for (int s=0;s<4;++s)
    #pragma unroll
    for (int i=0;i<4;++i) cs[s][i] = 0.f;

  for (int rt=0; rt<NT_; ++rt){
    const float* qp = Qg + (size_t)(rt*64 + wv*16 + l15)*D_ + quad*8;
    short8 bhi[2], blo[2];
    load_split8(qp,      bhi[0], blo[0]);
    load_split8(qp + 32, bhi[1], blo[1]);

    #pragma unroll
    for (int s=0;s<4;++s){
      float4v c = {0.f,0.f,0.f,0.f};
      #pragma unroll
      for (int cc=0; cc<2; ++cc){
        c = __builtin_amdgcn_mfma_f32_16x16x32_bf16(khi[s][cc], bhi[cc], c, 0,0,0);
        c = __builtin_amdgcn_mfma_f32_16x16x32_bf16(khi[s][cc], blo[cc], c, 0,0,0);
        c = __builtin_amdgcn_mfma_f32_16x16x32_bf16(klo[s][cc], bhi[cc], c, 0,0,0);
      }
      int kl = s*16 + quad*4;
      cs[s][0] += score_fn_m(c[0], msk[kl+0]);
      cs[s][1] += score_fn_m(c[1], msk[kl+1]);
      cs[s][2] += score_fn_m(c[2], msk[kl+2]);
      cs[s][3] += score_fn_m(c[3], msk[kl+3]);
    }
  }

  #pragma unroll
  for (int s=0;s<4;++s)
    #pragma unroll
    for (int i=0;i<4;++i){
      float v2 = cs[s][i];
      v2 += __shfl_xor(v2, 1);
      v2 += __shfl_xor(v2, 2);
      v2 += __shfl_xor(v2, 4);
      v2 += __shfl_xor(v2, 8);
      cs[s][i] = v2;
    }
  if (l15 == 0){
    #pragma unroll
    for (int s=0;s<4;++s)
      #pragma unroll
      for (int i=0;i<4;++i)
        red[(s*16 + quad*4 + i)*4 + wv] = cs[s][i];
  }
  __syncthreads();
  if (tid < 64){
    float t = red[tid*4+0] + red[tid*4+1] + red[tid*4+2] + red[tid*4+3];
    ncw[bh*N_ + kt*64 + tid] = 1.0f / sqrtf(t);
  }
}

__global__ __launch_bounds__(256) void spop_pass2(
    const float* __restrict__ Q, const float* __restrict__ K,
    const float* __restrict__ V, const int* __restrict__ mask,
    const float* __restrict__ w, float* __restrict__ out)
{
  __shared__ unsigned short Khi[64*LS], Klo[64*LS];
  __shared__ unsigned short Vt[64*LS];
  __shared__ unsigned short Ps[64*LS];
  __shared__ float msk[64], wms[64];

  const int rt = blockIdx.x, bh = blockIdx.y, b = bh>>3;
  const int tid = threadIdx.x;
  const int wv = tid>>6, lane = tid&63, quad = lane>>4, l15 = lane&15;

  const float* Qg = Q + (size_t)bh*N_*D_;
  const float* Kg = K + (size_t)bh*N_*D_;
  const float* Vg = V + (size_t)bh*N_*D_;

  short8 qhi[2], qlo[2];
  {
    const float* qp = Qg + (size_t)(rt*64 + wv*16 + l15)*D_ + quad*8;
    load_split8(qp,      qhi[0], qlo[0]);
    load_split8(qp + 32, qhi[1], qlo[1]);
  }

  float4v acc[4];
  #pragma unroll
  for (int i=0;i<4;++i) acc[i] = (float4v){0.f,0.f,0.f,0.f};
  float rs = 0.f;

  for (int kt=0; kt<NT_; ++kt){
    __syncthreads();
    #pragma unroll
    for (int it=0; it<4; ++it){
      int idx = tid + it*256;
      int r = idx>>4, d4 = (idx&15)<<2;
      const float4v v = *(const float4v*)(Kg + (size_t)(kt*64 + r)*D_ + d4);
      unsigned h0,l0,h1,l1;
      split2(v.x, v.y, h0, l0);
      split2(v.z, v.w, h1, l1);
      unsigned* KhiW = (unsigned*)Khi; unsigned* KloW = (unsigned*)Klo;
      int base = r*LSW + (d4>>1);
      KhiW[base] = h0; KhiW[base+1] = h1;
      KloW[base] = l0; KloW[base+1] = l1;
    }
    #pragma unroll
    for (int it=0; it<2; ++it){
      int u = tid + it*256;
      int kp = u & 31;
      int d4 = (u>>5)<<2;
      const float* vp = Vg + (size_t)(kt*64 + kp*2)*D_ + d4;
      float4v a0 = *(const float4v*)vp;
      float4v a1 = *(const float4v*)(vp + D_);
      unsigned* VtW = (unsigned*)Vt;
      VtW[(d4+0)*LSW + kp] = packbf2(a0.x, a1.x);
      VtW[(d4+1)*LSW + kp] = packbf2(a0.y, a1.y);
      VtW[(d4+2)*LSW + kp] = packbf2(a0.z, a1.z);
      VtW[(d4+3)*LSW + kp] = packbf2(a0.w, a1.w);
    }
    if (tid < 64){
      int gk = kt*64 + tid;
      msk[tid] = (mask[b*N_ + gk] == 0) ? 1.f : 0.f;
      wms[tid] = w[bh*N_ + gk];
    }
    __syncthreads();

    #pragma unroll
    for (int s=0;s<4;++s){
      float4v c = {0.f,0.f,0.f,0.f};
      #pragma unroll
      for (int cc=0; cc<2; ++cc){
        const short8 ahi = *(const short8*)&Khi[(s*16+l15)*LS + cc*32 + quad*8];
        const short8 alo = *(const short8*)&Klo[(s*16+l15)*LS + cc*32 + quad*8];
        c = __builtin_amdgcn_mfma_f32_16x16x32_bf16(ahi, qhi[cc], c, 0,0,0);
        c = __builtin_amdgcn_mfma_f32_16x16x32_bf16(ahi, qlo[cc], c, 0,0,0);
        c = __builtin_amdgcn_mfma_f32_16x16x32_bf16(alo, qhi[cc], c, 0,0,0);
      }
      int kl = s*16 + quad*4;
      float sc0 = score_fn_m(c[0], msk[kl+0]) * wms[kl+0];
      float sc1 = score_fn_m(c[1], msk[kl+1]) * wms[kl+1];
      float sc2 = score_fn_m(c[2], msk[kl+2]) * wms[kl+2];
      float sc3 = score_fn_m(c[3], msk[kl+3]) * wms[kl+3];
      rs += (sc0 + sc1) + (sc2 + sc3);
      unsigned* PsW = (unsigned*)Ps;
      int pb = (wv*16 + l15)*LSW + (kl>>1);
      PsW[pb]   = packbf2(sc0, sc1);
      PsW[pb+1] = packbf2(sc2, sc3);
    }

    short8 pf[2];
    pf[0] = *(const short8*)&Ps[(wv*16+l15)*LS +  0 + quad*8];
    pf[1] = *(const short8*)&Ps[(wv*16+l15)*LS + 32 + quad*8];
    #pragma unroll
    for (int s2=0;s2<4;++s2){
      #pragma unroll
      for (int cc=0; cc<2; ++cc){
        const short8 av = *(const short8*)&Vt[(s2*16+l15)*LS + cc*32 + quad*8];
        acc[s2] = __builtin_amdgcn_mfma_f32_16x16x32_bf16(av, pf[cc], acc[s2], 0,0,0);
      }
    }
  }

  rs += __shfl_xor(rs, 16);
  rs += __shfl_xor(rs, 32);
  float inv = 1.0f / fmaxf(rs, 1e-12f);

  float* Og = out + (size_t)bh*N_*D_ + (size_t)(rt*64 + wv*16 + l15)*D_;
  #pragma unroll
  for (int s2=0;s2<4;++s2)
    #pragma unroll
    for (int i=0;i<4;++i)
      Og[s2*16 + quad*4 + i] = acc[s2][i] * inv;
}

extern "C" void kernel_launch(void* const* d_in, const int* in_sizes, int n_in,
                              void* d_out, int out_size, void* d_ws, size_t ws_size,
                              hipStream_t stream) {
  (void)in_sizes; (void)n_in; (void)out_size;
  const float* Q   = (const float*)d_in[0];
  const float* K   = (const float*)d_in[1];
  const float* V   = (const float*)d_in[2];
  const int*  mask = (const int*)d_in[3];
  float* out = (float*)d_out;

  const size_t nc_bytes = (size_t)BH_*N_*sizeof(float);        // 128 KB
  const size_t vw_off   = 131072;
  const size_t vw_bytes = (size_t)BH_*NT_*10*512*2;            // 5.24 MB
  const size_t qk_off   = vw_off + vw_bytes;
  const size_t qk_one   = (size_t)BH_*N_*D_;
  const size_t qk_bytes = 4*qk_one*2;                          // 16.78 MB
  const size_t S_bytes  = (size_t)2*BH_*N_*N_;                 // 128 MiB
  const size_t need_A   = qk_off + qk_bytes + S_bytes;         // ~156.4 MB
  const size_t need_B   = qk_off + S_bytes;                    // ~139.6 MB

  if (ws_size >= need_A){
    float* nc = (float*)d_ws;
    unsigned short* Vw = (unsigned short*)((char*)d_ws + vw_off);
    unsigned short* Qh = (unsigned short*)((char*)d_ws + qk_off);
    unsigned short* Ql = Qh + qk_one;
    unsigned short* Kh = Ql + qk_one;
    unsigned short* Kl = Kh + qk_one;
    unsigned short* S  = (unsigned short*)((char*)d_ws + qk_off + qk_bytes);
    hipMemsetAsync(nc, 0, nc_bytes, stream);
    k0_split<<<dim3(2048), 256, 0, stream>>>(Q, K, Qh, Ql, Kh, Kl);
    k1_score<true><<<dim3(2048), 256, 0, stream>>>(
        nullptr, nullptr, Qh, Ql, Kh, Kl, nc, S);
    k2_pack<<<dim3(512), 256, 0, stream>>>(V, nc, mask, Vw);
    k3_stage<<<dim3(256), 1024, 0, stream>>>(S, Vw, out);
  } else if (ws_size >= need_B){
    float* nc = (float*)d_ws;
    unsigned short* Vw = (unsigned short*)((char*)d_ws + vw_off);
    unsigned short* S  = (unsigned short*)((char*)d_ws + qk_off);
    hipMemsetAsync(nc, 0, nc_bytes, stream);
    k1_score<false><<<dim3(2048), 256, 0, stream>>>(
        Q, K, nullptr, nullptr, nullptr, nullptr, nc, S);
    k2_pack<<<dim3(512), 256, 0, stream>>>(V, nc, mask, Vw);
    k3_stage<<<dim3(256), 1024, 0, stream>>>(S, Vw, out);
  } else {
    float* w = (float*)d_ws;
    k1_fallback<<<dim3(NT_, BH_), 256, 0, stream>>>(Q, K, mask, w);
    spop_pass2<<<dim3(NT_, BH_), 256, 0, stream>>>(Q, K, V, mask, w, out);
  }
}

// Round 10
// 164.121 us; speedup vs baseline: 1.0065x; 1.0065x over previous
//
#include <hip/hip_runtime.h>
#include <hip/hip_bf16.h>
#include <math.h>

#define B_ 2
#define H_ 8
#define N_ 2048
#define D_ 64
#define BH_ 16
#define NT_ (N_/64)
#define LS 72
#define LSW (LS/2)

typedef __attribute__((ext_vector_type(8))) short short8;
typedef __attribute__((ext_vector_type(4))) float float4v;
typedef __attribute__((ext_vector_type(2))) float float2v;

__device__ __forceinline__ float2v splat2(float s){ float2v v; v.x=s; v.y=s; return v; }

__device__ __forceinline__ unsigned packbf2(float a, float b){
  __hip_bfloat162 h = __float22bfloat162_rn(make_float2(a, b));
  return *(unsigned*)&h;
}
__device__ __forceinline__ void split2(float a, float b, unsigned& hi, unsigned& lo){
  hi = packbf2(a, b);
  float ha = __uint_as_float(hi << 16);
  float hb = __uint_as_float(hi & 0xFFFF0000u);
  lo = packbf2(a - ha, b - hb);
}
__device__ __forceinline__ void load_split8(const float* p, short8& hi8, short8& lo8){
  float4v v0 = *(const float4v*)p;
  float4v v1 = *(const float4v*)(p + 4);
  unsigned h0,h1,h2,h3,l0,l1,l2,l3;
  split2(v0.x, v0.y, h0, l0);
  split2(v0.z, v0.w, h1, l1);
  split2(v1.x, v1.y, h2, l2);
  split2(v1.z, v1.w, h3, l3);
  unsigned ph[4] = {h0,h1,h2,h3};
  unsigned pl[4] = {l0,l1,l2,l3};
  hi8 = *(short8*)ph;
  lo8 = *(short8*)pl;
}

// packed-pair score: (1 + acos(clip(qk)))^(-5) on two values at once.
__device__ __forceinline__ float2v score2(float2v qk){
  float2v ax;
  ax.x = fminf(fabsf(qk.x), 1.0f - 1e-7f);
  ax.y = fminf(fabsf(qk.y), 1.0f - 1e-7f);
  float2v p = __builtin_elementwise_fma(
                __builtin_elementwise_fma(
                  __builtin_elementwise_fma(splat2(-0.0187293f), ax, splat2(0.0742610f)),
                  ax, splat2(-0.2121144f)),
                ax, splat2(1.5707288f));
  float2v u = __builtin_elementwise_fma(ax, splat2(-1.0f), splat2(1.0f));
  float2v t;
  t.x = __builtin_amdgcn_sqrtf(u.x);
  t.y = __builtin_amdgcn_sqrtf(u.y);
  float2v t2 = t * p;
  float2v gn = __builtin_elementwise_fma(t2, splat2(-1.0f), splat2(3.14159265358979f));
  float2v g;
  g.x = (qk.x >= 0.0f) ? t2.x : gn.x;
  g.y = (qk.y >= 0.0f) ? t2.y : gn.y;
  float2v w1 = g + splat2(1.0f);
  float2v w2 = w1 * w1;
  float2v w4 = w2 * w2;
  float2v w5 = w4 * w1;
  float2v r;
  r.x = __builtin_amdgcn_rcpf(w5.x);
  r.y = __builtin_amdgcn_rcpf(w5.y);
  return r;
}

// scalar masked variant (fallback tier only)
__device__ __forceinline__ float score_fn_m(float qk, float masked){
  float ax = fminf(fabsf(qk), 1.0f - 1e-7f);
  float t  = __builtin_amdgcn_sqrtf(1.0f - ax);
  float p  = __builtin_fmaf(__builtin_fmaf(__builtin_fmaf(-0.0187293f, ax, 0.0742610f),
                                           ax, -0.2121144f), ax, 1.5707288f);
  float t2 = t * p;
  float g  = (qk >= 0.0f) ? t2 : (3.14159265358979f - t2);
  g = (masked != 0.0f) ? 10000.0f : g;
  float w1 = 1.0f + g;
  float w2 = w1*w1;
  float w4 = w2*w2;
  return __builtin_amdgcn_rcpf(w4*w1);
}

// k0: one-time fp32 -> bf16 hi/lo split of Q and K
__global__ __launch_bounds__(256) void k0_split(
    const float* __restrict__ Q, const float* __restrict__ K,
    unsigned short* __restrict__ Qh, unsigned short* __restrict__ Ql,
    unsigned short* __restrict__ Kh, unsigned short* __restrict__ Kl)
{
  size_t i = (size_t)blockIdx.x*256 + threadIdx.x;
  const size_t tot = (size_t)BH_*N_*D_/8;
  const float* src; unsigned short *dh, *dl;
  if (i < tot){ src = Q; dh = Qh; dl = Ql; }
  else        { src = K; dh = Kh; dl = Kl; i -= tot; }
  short8 hi, lo;
  load_split8(src + i*8, hi, lo);
  *(short8*)&dh[i*8] = hi;
  *(short8*)&dl[i*8] = lo;
}

// k1 (R5 base + chain split, 71.8us): UNMASKED scores -> S, col sums -> ncw.
// Do NOT thin the 4-s body (R2/R6 both regressed).
template<bool PRE>
__global__ __launch_bounds__(256) void k1_score(
    const float* __restrict__ Qf, const float* __restrict__ Kf,
    const unsigned short* __restrict__ Qh, const unsigned short* __restrict__ Ql,
    const unsigned short* __restrict__ Kh, const unsigned short* __restrict__ Kl,
    float* __restrict__ ncw, unsigned short* __restrict__ S)
{
  __shared__ float red[64*4];
  const int id = blockIdx.x;
  const int xcd = id & 7;
  const int r0 = id >> 3;             // [0,256)
  const int kt = r0 & 31;
  const int grp = r0 >> 5;            // [0,8)
  const int flat = grp*8 + xcd;       // [0,64)
  const int bh = flat & 15;
  const int rz = flat >> 4;           // [0,4)
  const int tid = threadIdx.x;
  const int wv = tid>>6, lane = tid&63, quad = lane>>4, l15 = lane&15;

  short8 khi[4][2], klo[4][2];
  if constexpr (PRE){
    #pragma unroll
    for (int s=0;s<4;++s){
      const size_t r = (size_t)(bh*N_ + kt*64 + s*16 + l15)*D_ + quad*8;
      khi[s][0] = *(const short8*)&Kh[r];
      khi[s][1] = *(const short8*)&Kh[r+32];
      klo[s][0] = *(const short8*)&Kl[r];
      klo[s][1] = *(const short8*)&Kl[r+32];
    }
  } else {
    #pragma unroll
    for (int s=0;s<4;++s){
      const float* kp = Kf + (size_t)(bh*N_ + kt*64 + s*16 + l15)*D_ + quad*8;
      load_split8(kp,      khi[s][0], klo[s][0]);
      load_split8(kp + 32, khi[s][1], klo[s][1]);
    }
  }

  float2v cs2[4][2];
  #pragma unroll
  for (int s=0;s<4;++s){ cs2[s][0] = splat2(0.f); cs2[s][1] = splat2(0.f); }

  const int iters = NT_/4;
  const int rt0 = rz*iters;

  const size_t qoff0 = (size_t)(bh*N_ + rt0*64 + wv*16 + l15)*D_ + quad*8;
  const unsigned lconst = (unsigned)(((quad>>1)<<7) + (l15<<3) + ((quad&1)<<2));
  unsigned short* Sp = S + ((((size_t)(bh*NT_ + kt)*NT_ + rt0)*4 + wv)<<10) + lconst;

  short8 qh0,qh1,ql0,ql1;
  if constexpr (PRE){
    const unsigned short* qp = Qh + qoff0;
    const unsigned short* lp = Ql + qoff0;
    qh0 = *(const short8*)qp;      qh1 = *(const short8*)(qp+32);
    ql0 = *(const short8*)lp;      ql1 = *(const short8*)(lp+32);
  } else {
    const float* qp = Qf + qoff0;
    load_split8(qp,      qh0, ql0);
    load_split8(qp + 32, qh1, ql1);
  }

  for (int rti=0; rti<iters; ++rti){
    short8 nh0,nh1,nl0,nl1;
    const size_t qoffn = qoff0 + (size_t)(rti + ((rti+1<iters) ? 1 : 0))*4096;
    if constexpr (PRE){
      const unsigned short* qp = Qh + qoffn;
      const unsigned short* lp = Ql + qoffn;
      nh0 = *(const short8*)qp;    nh1 = *(const short8*)(qp+32);
      nl0 = *(const short8*)lp;    nl1 = *(const short8*)(lp+32);
    } else {
      const float* qp = Qf + qoffn;
      load_split8(qp,      nh0, nl0);
      load_split8(qp + 32, nh1, nl1);
    }

    #pragma unroll
    for (int s=0;s<4;++s){
      float4v ca = {0.f,0.f,0.f,0.f};
      float4v cb = {0.f,0.f,0.f,0.f};
      ca = __builtin_amdgcn_mfma_f32_16x16x32_bf16(khi[s][0], qh0, ca, 0,0,0);
      cb = __builtin_amdgcn_mfma_f32_16x16x32_bf16(khi[s][1], qh1, cb, 0,0,0);
      ca = __builtin_amdgcn_mfma_f32_16x16x32_bf16(khi[s][0], ql0, ca, 0,0,0);
      cb = __builtin_amdgcn_mfma_f32_16x16x32_bf16(khi[s][1], ql1, cb, 0,0,0);
      ca = __builtin_amdgcn_mfma_f32_16x16x32_bf16(klo[s][0], qh0, ca, 0,0,0);
      cb = __builtin_amdgcn_mfma_f32_16x16x32_bf16(klo[s][1], qh1, cb, 0,0,0);
      float4v c = ca + cb;
      float2v c01; c01.x = c[0]; c01.y = c[1];
      float2v c23; c23.x = c[2]; c23.y = c[3];
      float2v s01 = score2(c01);
      float2v s23 = score2(c23);
      cs2[s][0] += s01;
      cs2[s][1] += s23;
      uint2 pk;
      pk.x = packbf2(s01.x, s01.y);
      pk.y = packbf2(s23.x, s23.y);
      *(uint2*)(Sp + (s<<8)) = pk;
    }
    Sp += 4096;
    qh0=nh0; qh1=nh1; ql0=nl0; ql1=nl1;
  }

  float cs[4][4];
  #pragma unroll
  for (int s=0;s<4;++s){
    cs[s][0]=cs2[s][0].x; cs[s][1]=cs2[s][0].y;
    cs[s][2]=cs2[s][1].x; cs[s][3]=cs2[s][1].y;
  }

  #pragma unroll
  for (int s=0;s<4;++s)
    #pragma unroll
    for (int i=0;i<4;++i){
      float v2 = cs[s][i];
      v2 += __shfl_xor(v2, 1);
      v2 += __shfl_xor(v2, 2);
      v2 += __shfl_xor(v2, 4);
      v2 += __shfl_xor(v2, 8);
      cs[s][i] = v2;
    }
  if (l15 == 0){
    #pragma unroll
    for (int s=0;s<4;++s)
      #pragma unroll
      for (int i=0;i<4;++i)
        red[(s*16 + quad*4 + i)*4 + wv] = cs[s][i];
  }
  __syncthreads();
  if (tid < 64){
    float t = red[tid*4+0] + red[tid*4+1] + red[tid*4+2] + red[tid*4+3];
    atomicAdd(&ncw[bh*N_ + kt*64 + tid], t);
  }
}

// k2_pack (+XCD swizzle matching k3): Vw written on the XCD that will read it.
__global__ __launch_bounds__(256) void k2_pack(
    const float* __restrict__ V, const float* __restrict__ nc,
    const int* __restrict__ mask, unsigned short* __restrict__ Vw)
{
  __shared__ float T[64*65];
  __shared__ float wrow[64];
  const int id = blockIdx.x;            // 512
  const int xcd = id & 7;
  const int r0 = id >> 3;               // 0..63
  const int bh = (r0 & 1)*8 + xcd;      // XCD = bh%8
  const int mt = r0 >> 1;               // 0..31
  const int tid = threadIdx.x;
  const float* Vg = V + (size_t)bh*N_*D_;
  const float* ncg = nc + (size_t)bh*N_;
  unsigned short* Fb = Vw + ((size_t)(bh*NT_ + mt)*10)*512;

  {
    int m = tid >> 2;
    int d0 = (tid & 3) * 16;
    int gm = mt*64 + m;
    float wm = (mask[(bh>>3)*N_ + gm] == 0) ? 0.0f
             : (1.0f / sqrtf(fmaxf(ncg[gm], 1e-30f)));
    if (d0 == 0) wrow[m] = wm;
    #pragma unroll
    for (int j=0;j<4;++j){
      float4v v = *(const float4v*)(Vg + (size_t)gm*D_ + d0 + j*4);
      T[(d0+j*4+0)*65 + m] = v.x*wm;
      T[(d0+j*4+1)*65 + m] = v.y*wm;
      T[(d0+j*4+2)*65 + m] = v.z*wm;
      T[(d0+j*4+3)*65 + m] = v.w*wm;
    }
  }
  __syncthreads();

  for (int idx = tid; idx < 640; idx += 256){
    int f = idx >> 6, lane = idx & 63;
    int quad = lane >> 4, l15 = lane & 15;
    int s2 = f >> 1, cc = f & 1;
    int m0 = cc*32 + quad*8;
    unsigned pk[4];
    if (s2 < 4){
      int d = s2*16 + l15;
      #pragma unroll
      for (int j=0;j<4;++j)
        pk[j] = packbf2(T[d*65 + m0 + 2*j], T[d*65 + m0 + 2*j + 1]);
    } else if (l15 == 0){
      #pragma unroll
      for (int j=0;j<4;++j)
        pk[j] = packbf2(wrow[m0 + 2*j], wrow[m0 + 2*j + 1]);
    } else {
      pk[0]=pk[1]=pk[2]=pk[3]=0u;
    }
    *(short8*)(Fb + ((size_t)f*64 + lane)*8) = *(short8*)pk;
  }
}

// k3_stage v3: TWO independent barrier domains per CU. 512-thread blocks
// (8 waves = 4 row-slots x 2 kt-halves), one rt (64 rows) per block, grid 512
// -> 2 blocks/CU (LDS 40KB x2 = 80KB). When one block drains at its barrier
// waiting on S, the other block issues -- doubles effective MLP vs the single
// 1024-thread domain. Same LDS Vw staging + XCD swizzle + T14 split as R8.
__global__ __launch_bounds__(512) void k3_stage(
    const unsigned short* __restrict__ S, const unsigned short* __restrict__ Vw,
    float* __restrict__ out)
{
  __shared__ unsigned short Vs[2*2*10*512];   // 40960 B: [buf][gg][f][lane*8]; Red overlay

  const int id = blockIdx.x;            // 512 blocks
  const int xcd = id & 7;
  const int r0 = id >> 3;               // 0..63
  const int rt = r0 & 31;
  const int bhh = r0 >> 5;              // 0..1
  const int bh = bhh*8 + xcd;           // XCD = bh%8

  const int tid = threadIdx.x;
  const int wvid = tid >> 6;            // 0..7
  const int g    = wvid >> 2;           // kt half: 0 -> kt 0..15, 1 -> 16..31
  const int slot = wvid & 3;            // 16-row slot within this rt
  const int lane = tid & 63, quad = lane >> 4, l15 = lane & 15;
  const int row = rt*64 + slot*16 + l15;

  const size_t sb0 = ((((size_t)bh*NT_ + g*16)*NT_ + rt)*4 + (size_t)slot)*1024
                   + (size_t)quad*128 + (size_t)l15*8;

  // staging chunks (1280 short8 per iteration over 512 threads, bijective):
  // c0 = tid        in [0,512)   -> gg=0, f=tid>>6 (0..7)
  // c1 = tid+512    in [512,1024)-> tid<128: gg=0,f=8..9 ; else gg=1,f=0..5
  // c2 = tid+1024   (tid<256)    -> gg=1, f=6..9
  const int g0f = tid >> 6, g0ln = tid & 63;
  const int c1 = tid + 512;
  const int gg1 = (c1 >= 640) ? 1 : 0;
  const int rem1 = c1 - gg1*640;
  const int f1 = rem1 >> 6, ln1 = rem1 & 63;
  const bool has2 = (tid < 256);
  const int rem2 = tid + 384;           // (tid+1024)-640, gg=1
  const int f2 = rem2 >> 6, ln2 = rem2 & 63;
  const size_t vwbh = (size_t)bh*NT_;

  float4v acc[4];
  #pragma unroll
  for (int i=0;i<4;++i) acc[i] = (float4v){0.f,0.f,0.f,0.f};
  float4v c5 = {0.f,0.f,0.f,0.f};

  // prologue: stage it=0 (kt=0 and kt=16) into buf 0
  {
    short8 a = *(const short8*)&Vw[(vwbh + 0)*5120 + (size_t)g0f*512 + g0ln*8];
    *(short8*)&Vs[((0*2 + 0)*10 + g0f)*512 + g0ln*8] = a;
    short8 b = *(const short8*)&Vw[(vwbh + (size_t)gg1*16)*5120 + (size_t)f1*512 + ln1*8];
    *(short8*)&Vs[((0*2 + gg1)*10 + f1)*512 + ln1*8] = b;
    if (has2){
      short8 c = *(const short8*)&Vw[(vwbh + 16)*5120 + (size_t)f2*512 + ln2*8];
      *(short8*)&Vs[((0*2 + 1)*10 + f2)*512 + ln2*8] = c;
    }
  }
  short8 npf0 = *(const short8*)&S[sb0];
  short8 npf1 = *(const short8*)&S[sb0 + 512];
  __syncthreads();

  for (int it = 0; it < 16; ++it){
    const int cur = it & 1, nxt = cur ^ 1;
    short8 pf0 = npf0, pf1 = npf1;
    short8 vwa, vwb, vwc;
    if (it < 15){
      // T14 split: issue next-iter Vw staging loads (L2-resident) + S prefetch;
      // LDS writes deferred until after the MFMA block.
      vwa = *(const short8*)&Vw[(vwbh + (size_t)(it + 1))*5120 + (size_t)g0f*512 + g0ln*8];
      vwb = *(const short8*)&Vw[(vwbh + (size_t)(gg1*16 + it + 1))*5120 + (size_t)f1*512 + ln1*8];
      if (has2)
        vwc = *(const short8*)&Vw[(vwbh + (size_t)(16 + it + 1))*5120 + (size_t)f2*512 + ln2*8];
      const size_t sb = sb0 + (size_t)(it+1)*131072;
      npf0 = *(const short8*)&S[sb];
      npf1 = *(const short8*)&S[sb + 512];
    }

    const unsigned short* Fl = &Vs[((cur*2 + g)*10) << 9] + (size_t)lane*8;
    short8 va[10];
    #pragma unroll
    for (int f=0; f<10; ++f)
      va[f] = *(const short8*)(Fl + ((size_t)f << 9));

    #pragma unroll
    for (int s2=0;s2<4;++s2){
      acc[s2] = __builtin_amdgcn_mfma_f32_16x16x32_bf16(va[s2*2+0], pf0, acc[s2], 0,0,0);
      acc[s2] = __builtin_amdgcn_mfma_f32_16x16x32_bf16(va[s2*2+1], pf1, acc[s2], 0,0,0);
    }
    c5 = __builtin_amdgcn_mfma_f32_16x16x32_bf16(va[8], pf0, c5, 0,0,0);
    c5 = __builtin_amdgcn_mfma_f32_16x16x32_bf16(va[9], pf1, c5, 0,0,0);

    if (it < 15){
      *(short8*)&Vs[((nxt*2 + 0)*10 + g0f)*512 + g0ln*8] = vwa;
      *(short8*)&Vs[((nxt*2 + gg1)*10 + f1)*512 + ln1*8] = vwb;
      if (has2)
        *(short8*)&Vs[((nxt*2 + 1)*10 + f2)*512 + ln2*8] = vwc;
    }
    __syncthreads();
  }

  // reduce across the two kt halves (Red overlays Vs; safe after last barrier)
  float* Red = (float*)Vs;
  if (g == 1){
    float* Rr = Red + (size_t)(slot*16 + l15)*68;
    #pragma unroll
    for (int s2=0;s2<4;++s2)
      #pragma unroll
      for (int i=0;i<4;++i)
        Rr[s2*16 + quad*4 + i] = acc[s2][i];
    if (quad == 0) Rr[64] = c5[0];
  }
  __syncthreads();
  if (g == 0){
    const float* Rr = Red + (size_t)(slot*16 + l15)*68;
    #pragma unroll
    for (int s2=0;s2<4;++s2)
      #pragma unroll
      for (int i=0;i<4;++i)
        acc[s2][i] += Rr[s2*16 + quad*4 + i];
    float rs = __shfl(c5[0], l15) + Rr[64];
    float inv = 1.0f / fmaxf(rs, 1e-12f);

    float* Og = out + (size_t)bh*N_*D_ + (size_t)row*D_;
    #pragma unroll
    for (int s2=0;s2<4;++s2)
      #pragma unroll
      for (int i=0;i<4;++i)
        Og[s2*16 + quad*4 + i] = acc[s2][i] * inv;
  }
}

// -------- tier C fallback (verified structure, unchanged semantics) --------
__global__ __launch_bounds__(256) void k1_fallback(
    const float* __restrict__ Q, const float* __restrict__ K,
    const int* __restrict__ mask, float* __restrict__ ncw)
{
  __shared__ float msk[64];
  __shared__ float red[64*4];
  const int kt = blockIdx.x, bh = blockIdx.y;
  const int tid = threadIdx.x;
  const int wv = tid>>6, lane = tid&63, quad = lane>>4, l15 = lane&15;

  const float* Qg = Q + (size_t)bh*N_*D_;
  const float* Kg = K + (size_t)bh*N_*D_;

  short8 khi[4][2], klo[4][2];
  #pragma unroll
  for (int s=0;s<4;++s){
    const float* kp = Kg + (size_t)(kt*64 + s*16 + l15)*D_ + quad*8;
    load_split8(kp,      khi[s][0], klo[s][0]);
    load_split8(kp + 32, khi[s][1], klo[s][1]);
  }
  if (tid < 64)
    msk[tid] = (mask[(bh>>3)*N_ + kt*64 + tid] == 0) ? 1.f : 0.f;
  __syncthreads();

  float cs[4][4];
  #pragma unroll
  for (int s=0;s<4;++s)
    #pragma unroll
    for (int i=0;i<4;++i) cs[s][i] = 0.f;

  for (int rt=0; rt<NT_; ++rt){
    const float* qp = Qg + (size_t)(rt*64 + wv*16 + l15)*D_ + quad*8;
    short8 bhi[2], blo[2];
    load_split8(qp,      bhi[0], blo[0]);
    load_split8(qp + 32, bhi[1], blo[1]);

    #pragma unroll
    for (int s=0;s<4;++s){
      float4v c = {0.f,0.f,0.f,0.f};
      #pragma unroll
      for (int cc=0; cc<2; ++cc){
        c = __builtin_amdgcn_mfma_f32_16x16x32_bf16(khi[s][cc], bhi[cc], c, 0,0,0);
        c = __builtin_amdgcn_mfma_f32_16x16x32_bf16(khi[s][cc], blo[cc], c, 0,0,0);
        c = __builtin_amdgcn_mfma_f32_16x16x32_bf16(klo[s][cc], bhi[cc], c, 0,0,0);
      }
      int kl = s*16 + quad*4;
      cs[s][0] += score_fn_m(c[0], msk[kl+0]);
      cs[s][1] += score_fn_m(c[1], msk[kl+1]);
      cs[s][2] += score_fn_m(c[2], msk[kl+2]);
      cs[s][3] += score_fn_m(c[3], msk[kl+3]);
    }
  }

  #pragma unroll
  for (int s=0;s<4;++s)
    #pragma unroll
    for (int i=0;i<4;++i){
      float v2 = cs[s][i];
      v2 += __shfl_xor(v2, 1);
      v2 += __shfl_xor(v2, 2);
      v2 += __shfl_xor(v2, 4);
      v2 += __shfl_xor(v2, 8);
      cs[s][i] = v2;
    }
  if (l15 == 0){
    #pragma unroll
    for (int s=0;s<4;++s)
      #pragma unroll
      for (int i=0;i<4;++i)
        red[(s*16 + quad*4 + i)*4 + wv] = cs[s][i];
  }
  __syncthreads();
  if (tid < 64){
    float t = red[tid*4+0] + red[tid*4+1] + red[tid*4+2] + red[tid*4+3];
    ncw[bh*N_ + kt*64 + tid] = 1.0f / sqrtf(t);
  }
}

__global__ __launch_bounds__(256) void spop_pass2(
    const float* __restrict__ Q, const float* __restrict__ K,
    const float* __restrict__ V, const int* __restrict__ mask,
    const float* __restrict__ w, float* __restrict__ out)
{
  __shared__ unsigned short Khi[64*LS], Klo[64*LS];
  __shared__ unsigned short Vt[64*LS];
  __shared__ unsigned short Ps[64*LS];
  __shared__ float msk[64], wms[64];

  const int rt = blockIdx.x, bh = blockIdx.y, b = bh>>3;
  const int tid = threadIdx.x;
  const int wv = tid>>6, lane = tid&63, quad = lane>>4, l15 = lane&15;

  const float* Qg = Q + (size_t)bh*N_*D_;
  const float* Kg = K + (size_t)bh*N_*D_;
  const float* Vg = V + (size_t)bh*N_*D_;

  short8 qhi[2], qlo[2];
  {
    const float* qp = Qg + (size_t)(rt*64 + wv*16 + l15)*D_ + quad*8;
    load_split8(qp,      qhi[0], qlo[0]);
    load_split8(qp + 32, qhi[1], qlo[1]);
  }

  float4v acc[4];
  #pragma unroll
  for (int i=0;i<4;++i) acc[i] = (float4v){0.f,0.f,0.f,0.f};
  float rs = 0.f;

  for (int kt=0; kt<NT_; ++kt){
    __syncthreads();
    #pragma unroll
    for (int it=0; it<4; ++it){
      int idx = tid + it*256;
      int r = idx>>4, d4 = (idx&15)<<2;
      const float4v v = *(const float4v*)(Kg + (size_t)(kt*64 + r)*D_ + d4);
      unsigned h0,l0,h1,l1;
      split2(v.x, v.y, h0, l0);
      split2(v.z, v.w, h1, l1);
      unsigned* KhiW = (unsigned*)Khi; unsigned* KloW = (unsigned*)Klo;
      int base = r*LSW + (d4>>1);
      KhiW[base] = h0; KhiW[base+1] = h1;
      KloW[base] = l0; KloW[base+1] = l1;
    }
    #pragma unroll
    for (int it=0; it<2; ++it){
      int u = tid + it*256;
      int kp = u & 31;
      int d4 = (u>>5)<<2;
      const float* vp = Vg + (size_t)(kt*64 + kp*2)*D_ + d4;
      float4v a0 = *(const float4v*)vp;
      float4v a1 = *(const float4v*)(vp + D_);
      unsigned* VtW = (unsigned*)Vt;
      VtW[(d4+0)*LSW + kp] = packbf2(a0.x, a1.x);
      VtW[(d4+1)*LSW + kp] = packbf2(a0.y, a1.y);
      VtW[(d4+2)*LSW + kp] = packbf2(a0.z, a1.z);
      VtW[(d4+3)*LSW + kp] = packbf2(a0.w, a1.w);
    }
    if (tid < 64){
      int gk = kt*64 + tid;
      msk[tid] = (mask[b*N_ + gk] == 0) ? 1.f : 0.f;
      wms[tid] = w[bh*N_ + gk];
    }
    __syncthreads();

    #pragma unroll
    for (int s=0;s<4;++s){
      float4v c = {0.f,0.f,0.f,0.f};
      #pragma unroll
      for (int cc=0; cc<2; ++cc){
        const short8 ahi = *(const short8*)&Khi[(s*16+l15)*LS + cc*32 + quad*8];
        const short8 alo = *(const short8*)&Klo[(s*16+l15)*LS + cc*32 + quad*8];
        c = __builtin_amdgcn_mfma_f32_16x16x32_bf16(ahi, qhi[cc], c, 0,0,0);
        c = __builtin_amdgcn_mfma_f32_16x16x32_bf16(ahi, qlo[cc], c, 0,0,0);
        c = __builtin_amdgcn_mfma_f32_16x16x32_bf16(alo, qhi[cc], c, 0,0,0);
      }
      int kl = s*16 + quad*4;
      float sc0 = score_fn_m(c[0], msk[kl+0]) * wms[kl+0];
      float sc1 = score_fn_m(c[1], msk[kl+1]) * wms[kl+1];
      float sc2 = score_fn_m(c[2], msk[kl+2]) * wms[kl+2];
      float sc3 = score_fn_m(c[3], msk[kl+3]) * wms[kl+3];
      rs += (sc0 + sc1) + (sc2 + sc3);
      unsigned* PsW = (unsigned*)Ps;
      int pb = (wv*16 + l15)*LSW + (kl>>1);
      PsW[pb]   = packbf2(sc0, sc1);
      PsW[pb+1] = packbf2(sc2, sc3);
    }

    short8 pf[2];
    pf[0] = *(const short8*)&Ps[(wv*16+l15)*LS +  0 + quad*8];
    pf[1] = *(const short8*)&Ps[(wv*16+l15)*LS + 32 + quad*8];
    #pragma unroll
    for (int s2=0;s2<4;++s2){
      #pragma unroll
      for (int cc=0; cc<2; ++cc){
        const short8 av = *(const short8*)&Vt[(s2*16+l15)*LS + cc*32 + quad*8];
        acc[s2] = __builtin_amdgcn_mfma_f32_16x16x32_bf16(av, pf[cc], acc[s2], 0,0,0);
      }
    }
  }

  rs += __shfl_xor(rs, 16);
  rs += __shfl_xor(rs, 32);
  float inv = 1.0f / fmaxf(rs, 1e-12f);

  float* Og = out + (size_t)bh*N_*D_ + (size_t)(rt*64 + wv*16 + l15)*D_;
  #pragma unroll
  for (int s2=0;s2<4;++s2)
    #pragma unroll
    for (int i=0;i<4;++i)
      Og[s2*16 + quad*4 + i] = acc[s2][i] * inv;
}

extern "C" void kernel_launch(void* const* d_in, const int* in_sizes, int n_in,
                              void* d_out, int out_size, void* d_ws, size_t ws_size,
                              hipStream_t stream) {
  (void)in_sizes; (void)n_in; (void)out_size;
  const float* Q   = (const float*)d_in[0];
  const float* K   = (const float*)d_in[1];
  const float* V   = (const float*)d_in[2];
  const int*  mask = (const int*)d_in[3];
  float* out = (float*)d_out;

  const size_t nc_bytes = (size_t)BH_*N_*sizeof(float);        // 128 KB
  const size_t vw_off   = 131072;
  const size_t vw_bytes = (size_t)BH_*NT_*10*512*2;            // 5.24 MB
  const size_t qk_off   = vw_off + vw_bytes;
  const size_t qk_one   = (size_t)BH_*N_*D_;
  const size_t qk_bytes = 4*qk_one*2;                          // 16.78 MB
  const size_t S_bytes  = (size_t)2*BH_*N_*N_;                 // 128 MiB
  const size_t need_A   = qk_off + qk_bytes + S_bytes;         // ~156.4 MB
  const size_t need_B   = qk_off + S_bytes;                    // ~139.6 MB

  if (ws_size >= need_A){
    float* nc = (float*)d_ws;
    unsigned short* Vw = (unsigned short*)((char*)d_ws + vw_off);
    unsigned short* Qh = (unsigned short*)((char*)d_ws + qk_off);
    unsigned short* Ql = Qh + qk_one;
    unsigned short* Kh = Ql + qk_one;
    unsigned short* Kl = Kh + qk_one;
    unsigned short* S  = (unsigned short*)((char*)d_ws + qk_off + qk_bytes);
    hipMemsetAsync(nc, 0, nc_bytes, stream);
    k0_split<<<dim3(2048), 256, 0, stream>>>(Q, K, Qh, Ql, Kh, Kl);
    k1_score<true><<<dim3(2048), 256, 0, stream>>>(
        nullptr, nullptr, Qh, Ql, Kh, Kl, nc, S);
    k2_pack<<<dim3(512), 256, 0, stream>>>(V, nc, mask, Vw);
    k3_stage<<<dim3(512), 512, 0, stream>>>(S, Vw, out);
  } else if (ws_size >= need_B){
    float* nc = (float*)d_ws;
    unsigned short* Vw = (unsigned short*)((char*)d_ws + vw_off);
    unsigned short* S  = (unsigned short*)((char*)d_ws + qk_off);
    hipMemsetAsync(nc, 0, nc_bytes, stream);
    k1_score<false><<<dim3(2048), 256, 0, stream>>>(
        Q, K, nullptr, nullptr, nullptr, nullptr, nc, S);
    k2_pack<<<dim3(512), 256, 0, stream>>>(V, nc, mask, Vw);
    k3_stage<<<dim3(512), 512, 0, stream>>>(S, Vw, out);
  } else {
    float* w = (float*)d_ws;
    k1_fallback<<<dim3(NT_, BH_), 256, 0, stream>>>(Q, K, mask, w);
    spop_pass2<<<dim3(NT_, BH_), 256, 0, stream>>>(Q, K, V, mask, w, out);
  }
}